// Round 1
// baseline (369.226 us; speedup 1.0000x reference)
//
#include <hip/hip_runtime.h>

#define N_IN_C  1000000
#define N_OUT_C 20000
#define BATCH_C 64

// Kernel 1: offsets[s] = first e with mask_col[e] >= s; offsets[N_OUT] = E.
// mask_col is sorted ascending, so each s is written by exactly one thread
// (the e where mask_col jumps across s), plus the tail by e == E-1.
__global__ void build_offsets_kernel(const int* __restrict__ mask_col,
                                     int* __restrict__ offsets,
                                     int E, int n_out) {
    int e = blockIdx.x * blockDim.x + threadIdx.x;
    if (e >= E) return;
    int c = mask_col[e];
    int cprev = (e == 0) ? -1 : mask_col[e - 1];
    for (int s = cprev + 1; s <= c; ++s) offsets[s] = e;
    if (e == E - 1) {
        for (int s = c + 1; s <= n_out; ++s) offsets[s] = E;
    }
}

// Kernel 2: one block (256 thr = 4 waves) per output segment s.
// Each wave handles 16 batches; k/mask_row chunk loaded once per wave into
// registers and reused across the 16 batches. acc[] is statically indexed
// (rule #20: runtime-indexed arrays spill to scratch).
template<bool USE_OFFSETS>
__launch_bounds__(256)
__global__ void seg_matvec_kernel(const float* __restrict__ x,
                                  const float* __restrict__ kern,
                                  const float* __restrict__ bias,
                                  const int* __restrict__ mask_row,
                                  const int* __restrict__ mask_col,
                                  const int* __restrict__ offsets,
                                  float* __restrict__ out) {
    const int s    = blockIdx.x;
    const int wave = threadIdx.x >> 6;
    const int lane = threadIdx.x & 63;

    int start, end;
    if constexpr (USE_OFFSETS) {
        start = offsets[s];
        end   = offsets[s + 1];
    } else {
        // Fallback: redundant per-thread binary search (only if ws too small).
        int lo = 0, hi = N_IN_C;
        while (lo < hi) { int mid = (lo + hi) >> 1; if (mask_col[mid] < s) lo = mid + 1; else hi = mid; }
        start = lo;
        hi = N_IN_C;
        while (lo < hi) { int mid = (lo + hi) >> 1; if (mask_col[mid] < s + 1) lo = mid + 1; else hi = mid; }
        end = lo;
    }

    float acc[16];
#pragma unroll
    for (int i = 0; i < 16; ++i) acc[i] = 0.f;

    for (int cs = start; cs < end; cs += 64) {
        const int e = cs + lane;
        const bool valid = (e < end);
        float kv = 0.f;
        int   rr = 0;
        if (valid) { kv = kern[e]; rr = mask_row[e]; }
#pragma unroll
        for (int i = 0; i < 16; ++i) {
            const int b = wave * 16 + i;
            float xv = valid ? x[(size_t)b * N_IN_C + rr] : 0.f;
            acc[i] += xv * kv;
        }
    }

    const float bs = bias[s];
#pragma unroll
    for (int i = 0; i < 16; ++i) {
        float v = acc[i];
#pragma unroll
        for (int off = 32; off > 0; off >>= 1) v += __shfl_xor(v, off, 64);
        if (lane == i) {  // after full butterfly every lane has the sum
            out[(size_t)(wave * 16 + i) * N_OUT_C + s] = v + bs;
        }
    }
}

extern "C" void kernel_launch(void* const* d_in, const int* in_sizes, int n_in,
                              void* d_out, int out_size, void* d_ws, size_t ws_size,
                              hipStream_t stream) {
    const float* x        = (const float*)d_in[0];
    const float* kern     = (const float*)d_in[1];
    const float* bias     = (const float*)d_in[2];
    const int*   mask_row = (const int*)d_in[3];
    const int*   mask_col = (const int*)d_in[4];
    float*       out      = (float*)d_out;

    const size_t off_bytes = (size_t)(N_OUT_C + 1) * sizeof(int);
    if (ws_size >= off_bytes) {
        int* offsets = (int*)d_ws;
        build_offsets_kernel<<<(N_IN_C + 255) / 256, 256, 0, stream>>>(
            mask_col, offsets, N_IN_C, N_OUT_C);
        seg_matvec_kernel<true><<<N_OUT_C, 256, 0, stream>>>(
            x, kern, bias, mask_row, mask_col, offsets, out);
    } else {
        seg_matvec_kernel<false><<<N_OUT_C, 256, 0, stream>>>(
            x, kern, bias, mask_row, mask_col, nullptr, out);
    }
}

// Round 3
// 361.298 us; speedup vs baseline: 1.0219x; 1.0219x over previous
//
#include <hip/hip_runtime.h>

#define N_IN_C  1000000
#define N_OUT_C 20000
#define BATCH_C 64

// Kernel 1: offsets[s] = first e with mask_col[e] >= s; offsets[N_OUT] = E.
// mask_col sorted ascending: every s in [0, N_OUT] is written by exactly one
// thread (where the value jumps across s), plus the tail by e == E-1.
__global__ void build_offsets_kernel(const int* __restrict__ mask_col,
                                     int* __restrict__ offsets,
                                     int E, int n_out) {
    int e = blockIdx.x * blockDim.x + threadIdx.x;
    if (e >= E) return;
    int c = mask_col[e];
    int cprev = (e == 0) ? -1 : mask_col[e - 1];
    for (int s = cprev + 1; s <= c; ++s) offsets[s] = e;
    if (e == E - 1) {
        for (int s = c + 1; s <= n_out; ++s) offsets[s] = E;
    }
}

// Kernel 2: one block (256 thr = 4 waves) per output segment s.
// Wave w handles batches [16w, 16w+16). kern/mask_row chunk loaded once per
// wave into registers, reused across 16 batches. Inner loop is branch-free:
// lane index clamped to end-1, kv zeroed for invalid lanes (FMA adds 0).
// Epilogue: merged butterfly — 16 accumulators reduced across 64 lanes in
// 17 shuffles (vs 96 for 16 independent butterflies).
__launch_bounds__(256)
__global__ void seg_matvec_kernel(const float* __restrict__ x,
                                  const float* __restrict__ kern,
                                  const float* __restrict__ bias,
                                  const int* __restrict__ mask_row,
                                  const int* __restrict__ offsets,
                                  float* __restrict__ out) {
    const int s    = blockIdx.x;
    const int wave = threadIdx.x >> 6;
    const int lane = threadIdx.x & 63;

    const int start = offsets[s];
    const int end   = offsets[s + 1];
    const float bs  = bias[s];

    if (start >= end) {
        // Empty segment: output is just bias.
        if (lane < 16) out[(size_t)(wave * 16 + lane) * N_OUT_C + s] = bs;
        return;
    }

    float acc[16];
#pragma unroll
    for (int i = 0; i < 16; ++i) acc[i] = 0.f;

    for (int cs = start; cs < end; cs += 64) {
        const int e  = cs + lane;
        const int ec = (e < end) ? e : (end - 1);   // clamp: always in-bounds
        float kv = kern[ec];
        if (e >= end) kv = 0.f;                     // invalid lanes contribute 0
        const int rr = mask_row[ec];
        const size_t col = (size_t)rr;
#pragma unroll
        for (int i = 0; i < 16; ++i) {
            const int b = wave * 16 + i;
            acc[i] += x[(size_t)b * N_IN_C + col] * kv;
        }
    }

    // Merged butterfly: after stages with masks 1,2,4,8 one register holds,
    // at lane L, the partial sum of acc[L&15] over L's 16-lane group; masks
    // 16,32 finish the cross-group sum.
    float t[8];
#pragma unroll
    for (int j = 0; j < 8; ++j) {
        float a = acc[2 * j], b = acc[2 * j + 1];
        float mine  = (lane & 1) ? b : a;
        float other = (lane & 1) ? a : b;
        t[j] = mine + __shfl_xor(other, 1, 64);
    }
    float u[4];
#pragma unroll
    for (int j = 0; j < 4; ++j) {
        float a = t[2 * j], b = t[2 * j + 1];
        float mine  = (lane & 2) ? b : a;
        float other = (lane & 2) ? a : b;
        u[j] = mine + __shfl_xor(other, 2, 64);
    }
    float w[2];
#pragma unroll
    for (int j = 0; j < 2; ++j) {
        float a = u[2 * j], b = u[2 * j + 1];
        float mine  = (lane & 4) ? b : a;
        float other = (lane & 4) ? a : b;
        w[j] = mine + __shfl_xor(other, 4, 64);
    }
    float v;
    {
        float a = w[0], b = w[1];
        float mine  = (lane & 8) ? b : a;
        float other = (lane & 8) ? a : b;
        v = mine + __shfl_xor(other, 8, 64);
    }
    v += __shfl_xor(v, 16, 64);
    v += __shfl_xor(v, 32, 64);

    if (lane < 16) {
        out[(size_t)(wave * 16 + lane) * N_OUT_C + s] = v + bs;
    }
}

extern "C" void kernel_launch(void* const* d_in, const int* in_sizes, int n_in,
                              void* d_out, int out_size, void* d_ws, size_t ws_size,
                              hipStream_t stream) {
    const float* x        = (const float*)d_in[0];
    const float* kern     = (const float*)d_in[1];
    const float* bias     = (const float*)d_in[2];
    const int*   mask_row = (const int*)d_in[3];
    const int*   mask_col = (const int*)d_in[4];
    float*       out      = (float*)d_out;

    int* offsets = (int*)d_ws;  // (N_OUT_C + 1) ints; ws is ample
    build_offsets_kernel<<<(N_IN_C + 255) / 256, 256, 0, stream>>>(
        mask_col, offsets, N_IN_C, N_OUT_C);
    seg_matvec_kernel<<<N_OUT_C, 256, 0, stream>>>(
        x, kern, bias, mask_row, offsets, out);
}